// Round 1
// baseline (472.166 us; speedup 1.0000x reference)
//
#include <hip/hip_runtime.h>

// AdjacencyMatrix reduces algebraically to:
//   v1 = W[0:1024,:]^T x          (32 MB of W)
//   v2 = W^T v1                   (full W, 268 MB)
//   v3 = W^T v2                   (full W, 268 MB)
//   v4[j] = (W^T v3)[j]  for j in last 256 columns only (8 MB)
//   out[t] = W[j,j] * v4[j],  j = N-256+t
// Memory-bound: ~576 MB ideal HBM traffic -> ~91 us at 6.3 TB/s.

namespace {
constexpr int N = 8192;
constexpr int IN_N = 1024;
constexpr int OUT_N = 256;
}

__global__ void zero_f32(float* __restrict__ p, int n) {
  int i = blockIdx.x * blockDim.x + threadIdx.x;
  if (i < n) p[i] = 0.0f;
}

// v_out[j] += sum_{i in [i0, i0+chunk)} W[i*N+j] * v_in[i]
// Consecutive lanes take consecutive j (x4 via float4) -> coalesced 16B/lane.
// blockIdx.y partitions the i-dimension; one atomicAdd per j per block.
__global__ void gemv_wt(const float* __restrict__ W,
                        const float* __restrict__ vin,
                        float* __restrict__ vout,
                        int i_chunk) {
  const int j = (blockIdx.x * blockDim.x + threadIdx.x) * 4;
  const int i0 = blockIdx.y * i_chunk;
  const float* __restrict__ wp = W + (size_t)i0 * N + j;
  const float* __restrict__ vp = vin + i0;
  float ax = 0.f, ay = 0.f, az = 0.f, aw = 0.f;
  for (int i = 0; i < i_chunk; ++i) {
    const float s = vp[i];
    const float4 w = *reinterpret_cast<const float4*>(wp);
    ax += w.x * s;
    ay += w.y * s;
    az += w.z * s;
    aw += w.w * s;
    wp += N;
  }
  atomicAdd(vout + j + 0, ax);
  atomicAdd(vout + j + 1, ay);
  atomicAdd(vout + j + 2, az);
  atomicAdd(vout + j + 3, aw);
}

// Same contraction but only for the last OUT_N columns of W.
// 256 threads <-> 256 consecutive j -> coalesced scalar loads.
__global__ void gemv_wt_tail(const float* __restrict__ W,
                             const float* __restrict__ vin,
                             float* __restrict__ vout,
                             int i_chunk) {
  const int j = N - OUT_N + threadIdx.x;
  const int i0 = blockIdx.x * i_chunk;
  const float* __restrict__ wp = W + (size_t)i0 * N + j;
  float acc = 0.f;
  for (int i = 0; i < i_chunk; ++i) {
    acc += *wp * vin[i0 + i];
    wp += N;
  }
  atomicAdd(vout + j, acc);
}

__global__ void diag_scale(const float* __restrict__ W,
                           const float* __restrict__ v4,
                           float* __restrict__ out) {
  const int t = threadIdx.x;
  const int j = N - OUT_N + t;
  out[t] = W[(size_t)j * N + j] * v4[j];
}

extern "C" void kernel_launch(void* const* d_in, const int* in_sizes, int n_in,
                              void* d_out, int out_size, void* d_ws, size_t ws_size,
                              hipStream_t stream) {
  const float* x = (const float*)d_in[0];   // [1,1024] f32
  const float* W = (const float*)d_in[1];   // [8192,8192] f32 row-major
  // d_in[2] = num_steps (always 4; structure below hardcodes the 4-step chain)

  float* ws = (float*)d_ws;                 // re-poisoned every call -> zero it
  float* v1 = ws;
  float* v2 = ws + N;
  float* v3 = ws + 2 * N;
  float* v4 = ws + 3 * N;
  float* out = (float*)d_out;

  zero_f32<<<(4 * N) / 256, 256, 0, stream>>>(ws, 4 * N);

  // v1 = W[0:1024,:]^T x  (32 MB; small chunks for enough blocks)
  {
    dim3 grid(N / (256 * 4), IN_N / 32);
    gemv_wt<<<grid, 256, 0, stream>>>(W, x, v1, 32);
  }
  // v2 = W^T v1  (full W; 8 j-blocks x 64 i-chunks = 512 blocks, 8 waves/CU)
  {
    dim3 grid(N / (256 * 4), N / 128);
    gemv_wt<<<grid, 256, 0, stream>>>(W, v1, v2, 128);
  }
  // v3 = W^T v2
  {
    dim3 grid(N / (256 * 4), N / 128);
    gemv_wt<<<grid, 256, 0, stream>>>(W, v2, v3, 128);
  }
  // v4 (last 256 entries only) = W^T v3 restricted to last 256 columns
  gemv_wt_tail<<<N / 128, OUT_N, 0, stream>>>(W, v3, v4, 128);

  // out[t] = W[j,j] * v4[j]
  diag_scale<<<1, OUT_N, 0, stream>>>(W, v4, out);
}

// Round 2
// 451.476 us; speedup vs baseline: 1.0458x; 1.0458x over previous
//
#include <hip/hip_runtime.h>

// AdjacencyMatrix reduces algebraically to:
//   v1 = W[0:1024,:]^T x          (32 MB of W)
//   v2 = W^T v1                   (full W, 268 MB)
//   v3 = W^T v2                   (full W, 268 MB)
//   v4[j] = (W^T v3)[j]  for j in last 256 columns only (8 MB)
//   out[t] = W[j,j] * v4[j],  j = N-256+t
// Memory-bound: ~576 MB ideal HBM traffic -> ~92 us at 6.3 TB/s.
// R1 ran GEMVs at ~1.7 TB/s: 512 blocks (2/CU) + runtime trip count = no MLP.
// R2: compile-time CHUNK=32, unroll 8, 2048 blocks (8/CU, full 32 waves/CU).

namespace {
constexpr int N = 8192;
constexpr int IN_N = 1024;
constexpr int OUT_N = 256;
}

__global__ void zero_f32(float* __restrict__ p, int n) {
  int i = blockIdx.x * blockDim.x + threadIdx.x;
  if (i < n) p[i] = 0.0f;
}

// v_out[j] += sum_{i in [i0, i0+CHUNK)} W[i*N+j] * v_in[i]
// Lane -> consecutive float4 of j (coalesced 1 KB per wave-load).
// blockIdx.y partitions i; one atomicAdd per j per block.
// CHUNK is compile-time so the unroll batches 8 independent float4 loads.
template <int CHUNK>
__global__ __launch_bounds__(256) void gemv_wt(const float* __restrict__ W,
                                               const float* __restrict__ vin,
                                               float* __restrict__ vout) {
  const int j4 = blockIdx.x * blockDim.x + threadIdx.x;  // float4 index
  const int j = j4 * 4;
  const int i0 = blockIdx.y * CHUNK;
  const float4* __restrict__ wp =
      reinterpret_cast<const float4*>(W + (size_t)i0 * N + j);
  const float* __restrict__ vp = vin + i0;
  float ax = 0.f, ay = 0.f, az = 0.f, aw = 0.f;
#pragma unroll 8
  for (int i = 0; i < CHUNK; ++i) {
    const float s = vp[i];
    const float4 w = wp[(size_t)i * (N / 4)];
    ax += w.x * s;
    ay += w.y * s;
    az += w.z * s;
    aw += w.w * s;
  }
  atomicAdd(vout + j + 0, ax);
  atomicAdd(vout + j + 1, ay);
  atomicAdd(vout + j + 2, az);
  atomicAdd(vout + j + 3, aw);
}

// Last OUT_N columns only: 64 threads x float4 covers 256 columns.
template <int CHUNK>
__global__ __launch_bounds__(64) void gemv_wt_tail(const float* __restrict__ W,
                                                   const float* __restrict__ vin,
                                                   float* __restrict__ vout) {
  const int j = N - OUT_N + threadIdx.x * 4;
  const int i0 = blockIdx.x * CHUNK;
  const float4* __restrict__ wp =
      reinterpret_cast<const float4*>(W + (size_t)i0 * N + j);
  const float* __restrict__ vp = vin + i0;
  float ax = 0.f, ay = 0.f, az = 0.f, aw = 0.f;
#pragma unroll 8
  for (int i = 0; i < CHUNK; ++i) {
    const float s = vp[i];
    const float4 w = wp[(size_t)i * (N / 4)];
    ax += w.x * s;
    ay += w.y * s;
    az += w.z * s;
    aw += w.w * s;
  }
  atomicAdd(vout + j + 0, ax);
  atomicAdd(vout + j + 1, ay);
  atomicAdd(vout + j + 2, az);
  atomicAdd(vout + j + 3, aw);
}

__global__ void diag_scale(const float* __restrict__ W,
                           const float* __restrict__ v4,
                           float* __restrict__ out) {
  const int t = threadIdx.x;
  const int j = N - OUT_N + t;
  out[t] = W[(size_t)j * N + j] * v4[j];
}

extern "C" void kernel_launch(void* const* d_in, const int* in_sizes, int n_in,
                              void* d_out, int out_size, void* d_ws, size_t ws_size,
                              hipStream_t stream) {
  const float* x = (const float*)d_in[0];   // [1,1024] f32
  const float* W = (const float*)d_in[1];   // [8192,8192] f32 row-major
  // d_in[2] = num_steps (always 4; chain below hardcodes 4 steps)

  float* ws = (float*)d_ws;                 // re-poisoned every call -> zero it
  float* v1 = ws;
  float* v2 = ws + N;
  float* v3 = ws + 2 * N;
  float* v4 = ws + 3 * N;
  float* out = (float*)d_out;

  zero_f32<<<(4 * N) / 256, 256, 0, stream>>>(ws, 4 * N);

  // v1 = W[0:1024,:]^T x  (32 MB)
  {
    dim3 grid(N / (256 * 4), IN_N / 32);   // 8 x 32 = 256 blocks
    gemv_wt<32><<<grid, 256, 0, stream>>>(W, x, v1);
  }
  // v2 = W^T v1  (full W; 8 x 256 = 2048 blocks -> 8 blocks/CU, 32 waves/CU)
  {
    dim3 grid(N / (256 * 4), N / 32);
    gemv_wt<32><<<grid, 256, 0, stream>>>(W, v1, v2);
  }
  // v3 = W^T v2
  {
    dim3 grid(N / (256 * 4), N / 32);
    gemv_wt<32><<<grid, 256, 0, stream>>>(W, v2, v3);
  }
  // v4 (last 256 entries only): 8192/32 = 256 blocks x 1 wave
  gemv_wt_tail<32><<<N / 32, 64, 0, stream>>>(W, v3, v4);

  // out[t] = W[j,j] * v4[j]
  diag_scale<<<1, OUT_N, 0, stream>>>(W, v4, out);
}